// Round 1
// 624.917 us; speedup vs baseline: 1.0624x; 1.0624x over previous
//
#include <hip/hip_runtime.h>
#include <hip/hip_bf16.h>

// TransformerShardA: 2-layer GPT-2 shard. B=1, S=2048, D=768, H=12, hd=64,
// FFN=3072. Inputs f32 (+int idx), output f32 [1,2048,768].
//
// Round 7 (this session R0->R1):
//  - mfma_gemm staging converted to __builtin_amdgcn_global_load_lds width=16
//    (async global->LDS DMA, no VGPR round trip; m193 A/B: +67% on this
//    structure). LDS dest layout was already linear-in-lane-order so it is a
//    drop-in: lds off = chunk*16B = wave_base + lane*16.
//  - BN=64 tile variant (2x2 waves of 64x32, acc[4][2]) for the N=768 GEMMs
//    (attn out-proj, ffn2): grid 96 -> 192 blocks (was starving 256 CUs).
// Flash attention / LN / transposes unchanged from round 6.

#define SEQ 2048
#define DIM 768
#define NH 12
#define HD 64
#define FFN 3072
#define QKVD (3 * DIM)

typedef __attribute__((ext_vector_type(8))) short short8;
typedef __attribute__((ext_vector_type(4))) float f32x4;

__device__ __forceinline__ ushort bf16bits(float v) {
    __hip_bfloat16 hb = __float2bfloat16(v);
    return *reinterpret_cast<ushort*>(&hb);
}

// async 16B global->LDS (gfx950 global_load_lds_dwordx4)
__device__ __forceinline__ void gload_lds16(const ushort* g, ushort* l) {
    __builtin_amdgcn_global_load_lds(
        (const __attribute__((address_space(1))) void*)g,
        (__attribute__((address_space(3))) void*)l, 16, 0, 0);
}

// ---------------- embedding + positional ----------------
__global__ void embed_kernel(const int* __restrict__ idx,
                             const float* __restrict__ emb,
                             const float* __restrict__ pe,
                             float* __restrict__ x) {
    int i = blockIdx.x * 256 + threadIdx.x;
    int s = i / DIM;
    int d = i - s * DIM;
    x[i] = emb[idx[s] * DIM + d] + pe[i];
}

// ---------------- weight transpose + cast: W[K,N] f32 -> WT[N,K] bf16 -------
__global__ void transpose_w(const float* __restrict__ W,
                            __hip_bfloat16* __restrict__ WT, int K, int N) {
    __shared__ float t[32][33];
    const float* Wp = W + (size_t)blockIdx.z * K * N;
    __hip_bfloat16* Tp = WT + (size_t)blockIdx.z * K * N;
    int k0 = blockIdx.y * 32, n0 = blockIdx.x * 32;
    int r = threadIdx.x >> 3, c4 = (threadIdx.x & 7) * 4;
    float4 v = *(const float4*)&Wp[(size_t)(k0 + r) * N + n0 + c4];
    t[r][c4 + 0] = v.x; t[r][c4 + 1] = v.y; t[r][c4 + 2] = v.z; t[r][c4 + 3] = v.w;
    __syncthreads();
    __hip_bfloat16* dst = &Tp[(size_t)(n0 + r) * K + k0 + c4];
#pragma unroll
    for (int j = 0; j < 4; ++j) dst[j] = __float2bfloat16(t[c4 + j][r]);
}

// ---------------- LayerNorm (one block per row), writes bf16 ----------------
__global__ void ln_kernel(const float* __restrict__ x,
                          const float* __restrict__ sc,
                          const float* __restrict__ bi,
                          __hip_bfloat16* __restrict__ h) {
    int row = blockIdx.x, tid = threadIdx.x;
    __shared__ float red[256];
    const float* xr = x + row * DIM;
    float v[3];
#pragma unroll
    for (int i = 0; i < 3; ++i) v[i] = xr[tid + i * 256];
    float s = v[0] + v[1] + v[2];
    red[tid] = s; __syncthreads();
    for (int t = 128; t > 0; t >>= 1) {
        if (tid < t) red[tid] += red[tid + t];
        __syncthreads();
    }
    float mean = red[0] * (1.0f / DIM);
    __syncthreads();
    float q = 0.f;
#pragma unroll
    for (int i = 0; i < 3; ++i) { float d = v[i] - mean; q += d * d; }
    red[tid] = q; __syncthreads();
    for (int t = 128; t > 0; t >>= 1) {
        if (tid < t) red[tid] += red[tid + t];
        __syncthreads();
    }
    float rstd = rsqrtf(red[0] * (1.0f / DIM) + 1e-5f);
#pragma unroll
    for (int i = 0; i < 3; ++i) {
        int d = tid + i * 256;
        h[row * DIM + d] = __float2bfloat16((v[i] - mean) * rstd * sc[d] + bi[d]);
    }
}

// ---------------- bf16 MFMA GEMM: C = [res +] act(A@W + bias) ---------------
// 128xBN tile, 4 waves. BN=128: waves 2x2 of 64x64 (acc[4][4]).
//                       BN=64 : waves 2x2 of 64x32 (acc[4][2]).
// Staging via global_load_lds width=16: LDS chunk c (16B) <- row c>>2, col8
// (c&3); lds offset c*16B is wave-uniform base + lane*16 -> DMA-compatible.
template <int BN, bool GELU, bool RES, bool OUTBF16>
__global__ __launch_bounds__(256) void mfma_gemm(
        const ushort* __restrict__ A, const ushort* __restrict__ WT,
        const float* __restrict__ bias, const float* __restrict__ res,
        void* __restrict__ Cout, int M, int N, int K) {
    constexpr int NT = BN / 32;          // B-frags per wave: 4 or 2
    __shared__ ushort As[128 * 32];
    __shared__ ushort Bs[BN * 32];
    int tid = threadIdx.x;
    int w = tid >> 6, lane = tid & 63;
    int wm = (w >> 1) * 64, wn = (w & 1) * (BN / 2);
    int bm = blockIdx.y * 128, bn = blockIdx.x * BN;
    int lm = lane & 15, q8 = (lane >> 4) * 8;

    f32x4 acc[4][NT];
#pragma unroll
    for (int i = 0; i < 4; ++i)
#pragma unroll
        for (int j = 0; j < NT; ++j) acc[i][j] = {0.f, 0.f, 0.f, 0.f};

    int c0 = tid, c1 = tid + 256;
    const ushort* pa0 = &A[(size_t)(bm + (c0 >> 2)) * K + (c0 & 3) * 8];
    const ushort* pa1 = &A[(size_t)(bm + (c1 >> 2)) * K + (c1 & 3) * 8];
    const ushort* pb0 = &WT[(size_t)(bn + (c0 >> 2)) * K + (c0 & 3) * 8];
    const ushort* pb1 = nullptr;
    if constexpr (BN == 128)
        pb1 = &WT[(size_t)(bn + (c1 >> 2)) * K + (c1 & 3) * 8];

    for (int k0 = 0; k0 < K; k0 += 32) {
        __syncthreads();   // prior iter's frag ds_reads done
        gload_lds16(pa0 + k0, &As[c0 * 8]);
        gload_lds16(pa1 + k0, &As[c1 * 8]);
        gload_lds16(pb0 + k0, &Bs[c0 * 8]);
        if constexpr (BN == 128)
            gload_lds16(pb1 + k0, &Bs[c1 * 8]);
        __syncthreads();   // compiler emits vmcnt(0) drain before barrier

        short8 af[4], bw[NT];
#pragma unroll
        for (int mt = 0; mt < 4; ++mt)
            af[mt] = *(const short8*)&As[(wm + mt * 16 + lm) * 32 + q8];
#pragma unroll
        for (int nt = 0; nt < NT; ++nt)
            bw[nt] = *(const short8*)&Bs[(wn + nt * 16 + lm) * 32 + q8];
#pragma unroll
        for (int mt = 0; mt < 4; ++mt)
#pragma unroll
            for (int nt = 0; nt < NT; ++nt)
                acc[mt][nt] = __builtin_amdgcn_mfma_f32_16x16x32_bf16(
                    af[mt], bw[nt], acc[mt][nt], 0, 0, 0);
    }

#pragma unroll
    for (int nt = 0; nt < NT; ++nt) {
        int col = bn + wn + nt * 16 + lm;
        float bv = bias[col];
#pragma unroll
        for (int mt = 0; mt < 4; ++mt) {
            int rowb = bm + wm + mt * 16 + (q8 >> 1);
#pragma unroll
            for (int r = 0; r < 4; ++r) {
                int row = rowb + r;
                float v = acc[mt][nt][r] + bv;
                if (GELU) v = 0.5f * v * (1.0f + erff(v * 0.70710678118654752f));
                if (RES) v += res[(size_t)row * N + col];
                if (OUTBF16)
                    ((__hip_bfloat16*)Cout)[(size_t)row * N + col] = __float2bfloat16(v);
                else
                    ((float*)Cout)[(size_t)row * N + col] = v;
            }
        }
    }
}

// ---------------- MFMA flash attention ----------------
// qkv: [SEQ, 3*DIM] bf16 (q/k/v at 0/DIM/2*DIM, inner [NH,HD]).
// o: [SEQ, DIM] bf16, head-major inner layout.
// Block = (pair, head): handles Q-tiles qt=pair and qt=31-pair (64 rows each)
// -> constant 33 K-tiles per block. 4 waves: wave w owns qrows w*16..w*16+15.
// S^T = K.Q^T: A-frag from Ks[key][dim], B-frag from Q[qrow][dim] (global).
// C/D: key=quad*4+reg, qrow=lane&15 -> per-lane scalar softmax state.
// P stored [qrow][key] bf16 per-wave (stride 72) -> B-frag for O^T = V^T.P^T.
__global__ __launch_bounds__(256) void flash_attn_kernel(
        const ushort* __restrict__ qkv, ushort* __restrict__ o) {
    int pair = blockIdx.x, head = blockIdx.y;
    int tid = threadIdx.x, w = tid >> 6, lane = tid & 63;
    int ln16 = lane & 15, quad = lane >> 4;

    __shared__ ushort Ks[64 * 72];      // [key][dim], pad 8
    __shared__ ushort Vt[64 * 72];      // [dim][key], pad 8
    __shared__ ushort Ps[4][16 * 72];   // per-wave [qrow][key], pad 8

#pragma unroll 1
    for (int ph = 0; ph < 2; ++ph) {
        int qt = ph ? (31 - pair) : pair;

        // Q B-frags (row-major [qrow][dim] -> operand1 = Q^T), reused all kt
        short8 qf[2];
        {
            const ushort* qp = &qkv[(size_t)(qt * 64 + w * 16 + ln16) * QKVD
                                    + head * HD + quad * 8];
            qf[0] = *(const short8*)qp;
            qf[1] = *(const short8*)(qp + 32);
        }

        float m_i = -1e30f, l_i = 0.f;
        f32x4 oacc[4];
#pragma unroll
        for (int mt = 0; mt < 4; ++mt) oacc[mt] = {0.f, 0.f, 0.f, 0.f};

        for (int kt = 0; kt <= qt; ++kt) {
            __syncthreads();   // prior PV done with Ks/Vt
            // ---- stage K (vectored) and V^T (scatter) ----
#pragma unroll
            for (int hh = 0; hh < 2; ++hh) {
                int t = hh * 256 + tid;
                int key = t >> 3, c8 = (t & 7) * 8;
                const ushort* kp = &qkv[(size_t)(kt * 64 + key) * QKVD + DIM
                                        + head * HD + c8];
                *(short8*)&Ks[key * 72 + c8] = *(const short8*)kp;
                short8 vv = *(const short8*)(kp + DIM);
#pragma unroll
                for (int j = 0; j < 8; ++j)
                    Vt[(c8 + j) * 72 + key] = ((const ushort*)&vv)[j];
            }
            __syncthreads();

            // ---- S^T = K.Q^T ----
            f32x4 s[4];
#pragma unroll
            for (int mt = 0; mt < 4; ++mt) {
                s[mt] = {0.f, 0.f, 0.f, 0.f};
#pragma unroll
                for (int kc = 0; kc < 2; ++kc) {
                    short8 kf = *(const short8*)&Ks[(mt * 16 + ln16) * 72
                                                    + kc * 32 + quad * 8];
                    s[mt] = __builtin_amdgcn_mfma_f32_16x16x32_bf16(
                        kf, qf[kc], s[mt], 0, 0, 0);
                }
            }

            // ---- scale + causal mask ----
            int qrow = qt * 64 + w * 16 + ln16;
            float sv[4][4];
#pragma unroll
            for (int mt = 0; mt < 4; ++mt)
#pragma unroll
                for (int r = 0; r < 4; ++r) {
                    float v = s[mt][r] * 0.125f;
                    int key = kt * 64 + mt * 16 + quad * 4 + r;
                    sv[mt][r] = (kt == qt && key > qrow) ? -1e30f : v;
                }

            // ---- online softmax (state per lane = per qrow) ----
            float tmax = -1e30f;
#pragma unroll
            for (int mt = 0; mt < 4; ++mt)
#pragma unroll
                for (int r = 0; r < 4; ++r) tmax = fmaxf(tmax, sv[mt][r]);
            tmax = fmaxf(tmax, __shfl_xor(tmax, 16));
            tmax = fmaxf(tmax, __shfl_xor(tmax, 32));
            float m_new = fmaxf(m_i, tmax);
            float alpha = __expf(m_i - m_new);
            m_i = m_new;

            float ls = 0.f;
#pragma unroll
            for (int mt = 0; mt < 4; ++mt) {
                union { ushort u[4]; unsigned long long ull; } pk;
#pragma unroll
                for (int r = 0; r < 4; ++r) {
                    float p = __expf(sv[mt][r] - m_new);
                    ls += p;
                    pk.u[r] = bf16bits(p);
                }
                *(unsigned long long*)&Ps[w][ln16 * 72 + mt * 16 + quad * 4] = pk.ull;
            }
            ls += __shfl_xor(ls, 16);
            ls += __shfl_xor(ls, 32);
            l_i = l_i * alpha + ls;

#pragma unroll
            for (int mt = 0; mt < 4; ++mt) {
                oacc[mt][0] *= alpha; oacc[mt][1] *= alpha;
                oacc[mt][2] *= alpha; oacc[mt][3] *= alpha;
            }

            // ---- O^T += V^T.P^T (P per-wave private: no barrier needed) ----
#pragma unroll
            for (int kc = 0; kc < 2; ++kc) {
                short8 pf = *(const short8*)&Ps[w][ln16 * 72 + kc * 32 + quad * 8];
#pragma unroll
                for (int mt = 0; mt < 4; ++mt) {
                    short8 vf = *(const short8*)&Vt[(mt * 16 + ln16) * 72
                                                    + kc * 32 + quad * 8];
                    oacc[mt] = __builtin_amdgcn_mfma_f32_16x16x32_bf16(
                        vf, pf, oacc[mt], 0, 0, 0);
                }
            }
        }

        // ---- epilogue: O^T[dim=quad*4+reg(+16mt)][qrow=ln16] ----
        float inv = 1.0f / l_i;
        int orow = qt * 64 + w * 16 + ln16;
#pragma unroll
        for (int mt = 0; mt < 4; ++mt)
#pragma unroll
            for (int r = 0; r < 4; ++r) {
                int dimc = head * HD + mt * 16 + quad * 4 + r;
                o[(size_t)orow * DIM + dimc] = bf16bits(oacc[mt][r] * inv);
            }
    }
}

extern "C" void kernel_launch(void* const* d_in, const int* in_sizes, int n_in,
                              void* d_out, int out_size, void* d_ws, size_t ws_size,
                              hipStream_t stream) {
    const int*   idx   = (const int*)  d_in[0];
    const float* emb   = (const float*)d_in[1];
    const float* pe    = (const float*)d_in[2];
    const float* qkv_w = (const float*)d_in[3];
    const float* qkv_b = (const float*)d_in[4];
    const float* out_w = (const float*)d_in[5];
    const float* out_b = (const float*)d_in[6];
    const float* ln1_s = (const float*)d_in[7];
    const float* ln1_b = (const float*)d_in[8];
    const float* ln2_s = (const float*)d_in[9];
    const float* ln2_b = (const float*)d_in[10];
    const float* w1    = (const float*)d_in[11];
    const float* b1    = (const float*)d_in[12];
    const float* w2    = (const float*)d_in[13];
    const float* b2    = (const float*)d_in[14];

    float* x = (float*)d_ws;                                   // [SEQ,DIM] f32
    __hip_bfloat16* h   = (__hip_bfloat16*)(x + SEQ * DIM);    // [SEQ,DIM] bf16 (also o)
    __hip_bfloat16* qkv = h + SEQ * DIM;                       // [SEQ,QKVD]
    __hip_bfloat16* ffa = qkv + (size_t)SEQ * QKVD;            // [SEQ,FFN]
    __hip_bfloat16* qkv_wT = ffa + (size_t)SEQ * FFN;          // [L,QKVD,DIM]
    __hip_bfloat16* out_wT = qkv_wT + (size_t)2 * QKVD * DIM;  // [L,DIM,DIM]
    __hip_bfloat16* w1T    = out_wT + (size_t)2 * DIM * DIM;   // [L,FFN,DIM]
    __hip_bfloat16* w2T    = w1T + (size_t)2 * FFN * DIM;      // [L,DIM,FFN]

    transpose_w<<<dim3(QKVD / 32, DIM / 32, 2), 256, 0, stream>>>(qkv_w, qkv_wT, DIM, QKVD);
    transpose_w<<<dim3(DIM / 32, DIM / 32, 2), 256, 0, stream>>>(out_w, out_wT, DIM, DIM);
    transpose_w<<<dim3(FFN / 32, DIM / 32, 2), 256, 0, stream>>>(w1, w1T, DIM, FFN);
    transpose_w<<<dim3(DIM / 32, FFN / 32, 2), 256, 0, stream>>>(w2, w2T, FFN, DIM);

    embed_kernel<<<SEQ * DIM / 256, 256, 0, stream>>>(idx, emb, pe, x);

    for (int l = 0; l < 2; ++l) {
        ln_kernel<<<SEQ, 256, 0, stream>>>(x, ln1_s + l * DIM, ln1_b + l * DIM, h);
        mfma_gemm<128, false, false, true><<<dim3(QKVD / 128, SEQ / 128), 256, 0, stream>>>(
            (const ushort*)h, (const ushort*)(qkv_wT + (size_t)l * QKVD * DIM),
            qkv_b + l * QKVD, nullptr, qkv, SEQ, QKVD, DIM);
        flash_attn_kernel<<<dim3(16, NH), 256, 0, stream>>>(
            (const ushort*)qkv, (ushort*)h);   // o aliases h
        mfma_gemm<64, false, true, false><<<dim3(DIM / 64, SEQ / 128), 256, 0, stream>>>(
            (const ushort*)h, (const ushort*)(out_wT + (size_t)l * DIM * DIM),
            out_b + l * DIM, x, x, SEQ, DIM, DIM);
        ln_kernel<<<SEQ, 256, 0, stream>>>(x, ln2_s + l * DIM, ln2_b + l * DIM, h);
        mfma_gemm<128, true, false, true><<<dim3(FFN / 128, SEQ / 128), 256, 0, stream>>>(
            (const ushort*)h, (const ushort*)(w1T + (size_t)l * FFN * DIM),
            b1 + l * FFN, nullptr, ffa, SEQ, FFN, DIM);
        float* cdst = (l == 1) ? (float*)d_out : x;
        mfma_gemm<64, false, true, false><<<dim3(DIM / 64, SEQ / 128), 256, 0, stream>>>(
            (const ushort*)ffa, (const ushort*)(w2T + (size_t)l * DIM * FFN),
            b2 + l * DIM, x, cdst, SEQ, DIM, FFN);
    }
}

// Round 3
// 617.300 us; speedup vs baseline: 1.0755x; 1.0123x over previous
//
#include <hip/hip_runtime.h>
#include <hip/hip_bf16.h>

// TransformerShardA: 2-layer GPT-2 shard. B=1, S=2048, D=768, H=12, hd=64,
// FFN=3072. Inputs f32 (+int idx), output f32 [1,2048,768].
//
// Round 9 (session R2->R3): RESUBMIT of R2 unchanged (infra failure, no
// kernel verdict). Attention overhaul, GEMMs frozen (R1 state):
//  - grid 192 -> 384 blocks (one 64-row Q-tile per block), flat index with
//    heavy blocks (qt=31) first; 2-3 blocks/CU co-resident (LDS 43 KB).
//  - double-buffered K/V LDS, ONE barrier per K-tile (was 2), T14 split:
//    next tile's global loads issued before compute, LDS writes after.
//  - V^T staging conflict fix: unpadded [64][64] with key-group XOR swizzle
//    g' = g ^ ((row>>3)&7) on BOTH write and read (was 16-way ds_write_b16
//    conflict at stride 72: 8x72 elem == 0 mod bank period; padding cannot
//    fix, swizzle can). Writes now 2 lanes/bank (free).
//  - causal mask only on diagonal tile (wave-uniform branch).

#define SEQ 2048
#define DIM 768
#define NH 12
#define HD 64
#define FFN 3072
#define QKVD (3 * DIM)

typedef __attribute__((ext_vector_type(8))) short short8;
typedef __attribute__((ext_vector_type(4))) float f32x4;

__device__ __forceinline__ ushort bf16bits(float v) {
    __hip_bfloat16 hb = __float2bfloat16(v);
    return *reinterpret_cast<ushort*>(&hb);
}

// async 16B global->LDS (gfx950 global_load_lds_dwordx4)
__device__ __forceinline__ void gload_lds16(const ushort* g, ushort* l) {
    __builtin_amdgcn_global_load_lds(
        (const __attribute__((address_space(1))) void*)g,
        (__attribute__((address_space(3))) void*)l, 16, 0, 0);
}

// ---------------- embedding + positional ----------------
__global__ void embed_kernel(const int* __restrict__ idx,
                             const float* __restrict__ emb,
                             const float* __restrict__ pe,
                             float* __restrict__ x) {
    int i = blockIdx.x * 256 + threadIdx.x;
    int s = i / DIM;
    int d = i - s * DIM;
    x[i] = emb[idx[s] * DIM + d] + pe[i];
}

// ---------------- weight transpose + cast: W[K,N] f32 -> WT[N,K] bf16 -------
__global__ void transpose_w(const float* __restrict__ W,
                            __hip_bfloat16* __restrict__ WT, int K, int N) {
    __shared__ float t[32][33];
    const float* Wp = W + (size_t)blockIdx.z * K * N;
    __hip_bfloat16* Tp = WT + (size_t)blockIdx.z * K * N;
    int k0 = blockIdx.y * 32, n0 = blockIdx.x * 32;
    int r = threadIdx.x >> 3, c4 = (threadIdx.x & 7) * 4;
    float4 v = *(const float4*)&Wp[(size_t)(k0 + r) * N + n0 + c4];
    t[r][c4 + 0] = v.x; t[r][c4 + 1] = v.y; t[r][c4 + 2] = v.z; t[r][c4 + 3] = v.w;
    __syncthreads();
    __hip_bfloat16* dst = &Tp[(size_t)(n0 + r) * K + k0 + c4];
#pragma unroll
    for (int j = 0; j < 4; ++j) dst[j] = __float2bfloat16(t[c4 + j][r]);
}

// ---------------- LayerNorm (one block per row), writes bf16 ----------------
__global__ void ln_kernel(const float* __restrict__ x,
                          const float* __restrict__ sc,
                          const float* __restrict__ bi,
                          __hip_bfloat16* __restrict__ h) {
    int row = blockIdx.x, tid = threadIdx.x;
    __shared__ float red[256];
    const float* xr = x + row * DIM;
    float v[3];
#pragma unroll
    for (int i = 0; i < 3; ++i) v[i] = xr[tid + i * 256];
    float s = v[0] + v[1] + v[2];
    red[tid] = s; __syncthreads();
    for (int t = 128; t > 0; t >>= 1) {
        if (tid < t) red[tid] += red[tid + t];
        __syncthreads();
    }
    float mean = red[0] * (1.0f / DIM);
    __syncthreads();
    float q = 0.f;
#pragma unroll
    for (int i = 0; i < 3; ++i) { float d = v[i] - mean; q += d * d; }
    red[tid] = q; __syncthreads();
    for (int t = 128; t > 0; t >>= 1) {
        if (tid < t) red[tid] += red[tid + t];
        __syncthreads();
    }
    float rstd = rsqrtf(red[0] * (1.0f / DIM) + 1e-5f);
#pragma unroll
    for (int i = 0; i < 3; ++i) {
        int d = tid + i * 256;
        h[row * DIM + d] = __float2bfloat16((v[i] - mean) * rstd * sc[d] + bi[d]);
    }
}

// ---------------- bf16 MFMA GEMM: C = [res +] act(A@W + bias) ---------------
// 128xBN tile, 4 waves. BN=128: waves 2x2 of 64x64 (acc[4][4]).
//                       BN=64 : waves 2x2 of 64x32 (acc[4][2]).
// Staging via global_load_lds width=16 (linear-in-lane-order LDS dest).
template <int BN, bool GELU, bool RES, bool OUTBF16>
__global__ __launch_bounds__(256) void mfma_gemm(
        const ushort* __restrict__ A, const ushort* __restrict__ WT,
        const float* __restrict__ bias, const float* __restrict__ res,
        void* __restrict__ Cout, int M, int N, int K) {
    constexpr int NT = BN / 32;          // B-frags per wave: 4 or 2
    __shared__ ushort As[128 * 32];
    __shared__ ushort Bs[BN * 32];
    int tid = threadIdx.x;
    int w = tid >> 6, lane = tid & 63;
    int wm = (w >> 1) * 64, wn = (w & 1) * (BN / 2);
    int bm = blockIdx.y * 128, bn = blockIdx.x * BN;
    int lm = lane & 15, q8 = (lane >> 4) * 8;

    f32x4 acc[4][NT];
#pragma unroll
    for (int i = 0; i < 4; ++i)
#pragma unroll
        for (int j = 0; j < NT; ++j) acc[i][j] = {0.f, 0.f, 0.f, 0.f};

    int c0 = tid, c1 = tid + 256;
    const ushort* pa0 = &A[(size_t)(bm + (c0 >> 2)) * K + (c0 & 3) * 8];
    const ushort* pa1 = &A[(size_t)(bm + (c1 >> 2)) * K + (c1 & 3) * 8];
    const ushort* pb0 = &WT[(size_t)(bn + (c0 >> 2)) * K + (c0 & 3) * 8];
    const ushort* pb1 = nullptr;
    if constexpr (BN == 128)
        pb1 = &WT[(size_t)(bn + (c1 >> 2)) * K + (c1 & 3) * 8];

    for (int k0 = 0; k0 < K; k0 += 32) {
        __syncthreads();   // prior iter's frag ds_reads done
        gload_lds16(pa0 + k0, &As[c0 * 8]);
        gload_lds16(pa1 + k0, &As[c1 * 8]);
        gload_lds16(pb0 + k0, &Bs[c0 * 8]);
        if constexpr (BN == 128)
            gload_lds16(pb1 + k0, &Bs[c1 * 8]);
        __syncthreads();   // compiler emits vmcnt(0) drain before barrier

        short8 af[4], bw[NT];
#pragma unroll
        for (int mt = 0; mt < 4; ++mt)
            af[mt] = *(const short8*)&As[(wm + mt * 16 + lm) * 32 + q8];
#pragma unroll
        for (int nt = 0; nt < NT; ++nt)
            bw[nt] = *(const short8*)&Bs[(wn + nt * 16 + lm) * 32 + q8];
#pragma unroll
        for (int mt = 0; mt < 4; ++mt)
#pragma unroll
            for (int nt = 0; nt < NT; ++nt)
                acc[mt][nt] = __builtin_amdgcn_mfma_f32_16x16x32_bf16(
                    af[mt], bw[nt], acc[mt][nt], 0, 0, 0);
    }

#pragma unroll
    for (int nt = 0; nt < NT; ++nt) {
        int col = bn + wn + nt * 16 + lm;
        float bv = bias[col];
#pragma unroll
        for (int mt = 0; mt < 4; ++mt) {
            int rowb = bm + wm + mt * 16 + (q8 >> 1);
#pragma unroll
            for (int r = 0; r < 4; ++r) {
                int row = rowb + r;
                float v = acc[mt][nt][r] + bv;
                if (GELU) v = 0.5f * v * (1.0f + erff(v * 0.70710678118654752f));
                if (RES) v += res[(size_t)row * N + col];
                if (OUTBF16)
                    ((__hip_bfloat16*)Cout)[(size_t)row * N + col] = __float2bfloat16(v);
                else
                    ((float*)Cout)[(size_t)row * N + col] = v;
            }
        }
    }
}

// ---------------- MFMA flash attention ----------------
// qkv: [SEQ, 3*DIM] bf16 (q/k/v at 0/DIM/2*DIM, inner [NH,HD]).
// o: [SEQ, DIM] bf16.
// Block i of 384: qt = 31 - i/12 (heavy first), head = i%12. 64 Q-rows,
// 4 waves (wave w owns qrows w*16..w*16+15), kt = 0..qt K-tiles.
// S^T = K.Q^T (C/D: key=quad*4+reg, qrow=lane&15) -> per-lane softmax state.
// Double-buffered Ks/Vt, 1 barrier/tile; next tile's global loads issued
// before compute (T14). Vt: [row=dim][8 key-grps][8], grp XOR (row>>3)&7.
__global__ __launch_bounds__(256) void flash_attn_kernel(
        const ushort* __restrict__ qkv, ushort* __restrict__ o) {
    int bi = blockIdx.x;
    int qt = 31 - bi / NH, head = bi % NH;
    int tid = threadIdx.x, w = tid >> 6, lane = tid & 63;
    int ln16 = lane & 15, quad = lane >> 4;

    __shared__ ushort Ks[2][64 * 72];   // [key][dim], pad 8
    __shared__ ushort Vt[2][64 * 64];   // [dim][grp^swz][8], no pad
    __shared__ ushort Ps[4][16 * 72];   // per-wave [qrow][key], pad 8

    // staging coords (per hh half): key = (hh*256+tid)>>3, c8 = (tid&7)*8
    int skey[2], sc8;
    sc8 = (tid & 7) * 8;
    skey[0] = tid >> 3;
    skey[1] = (256 + tid) >> 3;

    short8 kst[2], vst[2];
    const ushort* kbase = qkv + DIM + head * HD + sc8;

    // ---- Q B-frags (row-major [qrow][dim] -> operand1 = Q^T) ----
    short8 qf[2];
    {
        const ushort* qp = &qkv[(size_t)(qt * 64 + w * 16 + ln16) * QKVD
                                + head * HD + quad * 8];
        qf[0] = *(const short8*)qp;
        qf[1] = *(const short8*)(qp + 32);
    }

    // ---- prologue: stage kt=0 into buf 0 ----
#pragma unroll
    for (int hh = 0; hh < 2; ++hh) {
        const ushort* kp = kbase + (size_t)(0 * 64 + skey[hh]) * QKVD;
        kst[hh] = *(const short8*)kp;
        vst[hh] = *(const short8*)(kp + DIM);
    }
#pragma unroll
    for (int hh = 0; hh < 2; ++hh) {
        int key = skey[hh];
        *(short8*)&Ks[0][key * 72 + sc8] = kst[hh];
        int g0 = key >> 3, ke = key & 7;
#pragma unroll
        for (int j = 0; j < 8; ++j) {
            int r = sc8 + j;
            Vt[0][r * 64 + ((g0 ^ (r >> 3)) & 7) * 8 + ke] = ((ushort*)&vst[hh])[j];
        }
    }
    __syncthreads();

    float m_i = -1e30f, l_i = 0.f;
    f32x4 oacc[4];
#pragma unroll
    for (int mt = 0; mt < 4; ++mt) oacc[mt] = {0.f, 0.f, 0.f, 0.f};

    int cur = 0;
    for (int kt = 0; kt <= qt; ++kt) {
        bool pre = (kt < qt);
        // ---- T14: issue next tile's global loads before compute ----
        if (pre) {
#pragma unroll
            for (int hh = 0; hh < 2; ++hh) {
                const ushort* kp = kbase + (size_t)((kt + 1) * 64 + skey[hh]) * QKVD;
                kst[hh] = *(const short8*)kp;
                vst[hh] = *(const short8*)(kp + DIM);
            }
        }

        // ---- S^T = K.Q^T ----
        f32x4 s[4];
#pragma unroll
        for (int mt = 0; mt < 4; ++mt) {
            s[mt] = {0.f, 0.f, 0.f, 0.f};
#pragma unroll
            for (int kc = 0; kc < 2; ++kc) {
                short8 kf = *(const short8*)&Ks[cur][(mt * 16 + ln16) * 72
                                                     + kc * 32 + quad * 8];
                s[mt] = __builtin_amdgcn_mfma_f32_16x16x32_bf16(
                    kf, qf[kc], s[mt], 0, 0, 0);
            }
        }

        // ---- scale (+ causal mask on diagonal tile only) ----
        int qrow = qt * 64 + w * 16 + ln16;
        float sv[4][4];
        if (kt == qt) {
#pragma unroll
            for (int mt = 0; mt < 4; ++mt)
#pragma unroll
                for (int r = 0; r < 4; ++r) {
                    int key = kt * 64 + mt * 16 + quad * 4 + r;
                    sv[mt][r] = (key > qrow) ? -1e30f : s[mt][r] * 0.125f;
                }
        } else {
#pragma unroll
            for (int mt = 0; mt < 4; ++mt)
#pragma unroll
                for (int r = 0; r < 4; ++r) sv[mt][r] = s[mt][r] * 0.125f;
        }

        // ---- online softmax (state per lane = per qrow) ----
        float tmax = -1e30f;
#pragma unroll
        for (int mt = 0; mt < 4; ++mt)
#pragma unroll
            for (int r = 0; r < 4; ++r) tmax = fmaxf(tmax, sv[mt][r]);
        tmax = fmaxf(tmax, __shfl_xor(tmax, 16));
        tmax = fmaxf(tmax, __shfl_xor(tmax, 32));
        float m_new = fmaxf(m_i, tmax);
        float alpha = __expf(m_i - m_new);
        m_i = m_new;

        float ls = 0.f;
#pragma unroll
        for (int mt = 0; mt < 4; ++mt) {
            union { ushort u[4]; unsigned long long ull; } pk;
#pragma unroll
            for (int r = 0; r < 4; ++r) {
                float p = __expf(sv[mt][r] - m_new);
                ls += p;
                pk.u[r] = bf16bits(p);
            }
            *(unsigned long long*)&Ps[w][ln16 * 72 + mt * 16 + quad * 4] = pk.ull;
        }
        ls += __shfl_xor(ls, 16);
        ls += __shfl_xor(ls, 32);
        l_i = l_i * alpha + ls;

#pragma unroll
        for (int mt = 0; mt < 4; ++mt) {
            oacc[mt][0] *= alpha; oacc[mt][1] *= alpha;
            oacc[mt][2] *= alpha; oacc[mt][3] *= alpha;
        }

        // ---- O^T += V^T.P^T (P per-wave private: no barrier needed) ----
#pragma unroll
        for (int kc = 0; kc < 2; ++kc) {
            short8 pf = *(const short8*)&Ps[w][ln16 * 72 + kc * 32 + quad * 8];
#pragma unroll
            for (int mt = 0; mt < 4; ++mt) {
                int row = mt * 16 + ln16;
                int g = kc * 4 + quad;
                short8 vf = *(const short8*)&Vt[cur][row * 64
                                                     + ((g ^ (row >> 3)) & 7) * 8];
                oacc[mt] = __builtin_amdgcn_mfma_f32_16x16x32_bf16(
                    vf, pf, oacc[mt], 0, 0, 0);
            }
        }

        // ---- write next tile to other buffer, single barrier ----
        if (pre) {
            int nb = cur ^ 1;
#pragma unroll
            for (int hh = 0; hh < 2; ++hh) {
                int key = skey[hh];
                *(short8*)&Ks[nb][key * 72 + sc8] = kst[hh];
                int g0 = key >> 3, ke = key & 7;
#pragma unroll
                for (int j = 0; j < 8; ++j) {
                    int r = sc8 + j;
                    Vt[nb][r * 64 + ((g0 ^ (r >> 3)) & 7) * 8 + ke] =
                        ((ushort*)&vst[hh])[j];
                }
            }
        }
        __syncthreads();
        cur ^= 1;
    }

    // ---- epilogue: O^T[dim=quad*4+reg(+16mt)][qrow=ln16] ----
    float inv = 1.0f / l_i;
    int orow = qt * 64 + w * 16 + ln16;
#pragma unroll
    for (int mt = 0; mt < 4; ++mt)
#pragma unroll
        for (int r = 0; r < 4; ++r) {
            int dimc = head * HD + mt * 16 + quad * 4 + r;
            o[(size_t)orow * DIM + dimc] = bf16bits(oacc[mt][r] * inv);
        }
}

extern "C" void kernel_launch(void* const* d_in, const int* in_sizes, int n_in,
                              void* d_out, int out_size, void* d_ws, size_t ws_size,
                              hipStream_t stream) {
    const int*   idx   = (const int*)  d_in[0];
    const float* emb   = (const float*)d_in[1];
    const float* pe    = (const float*)d_in[2];
    const float* qkv_w = (const float*)d_in[3];
    const float* qkv_b = (const float*)d_in[4];
    const float* out_w = (const float*)d_in[5];
    const float* out_b = (const float*)d_in[6];
    const float* ln1_s = (const float*)d_in[7];
    const float* ln1_b = (const float*)d_in[8];
    const float* ln2_s = (const float*)d_in[9];
    const float* ln2_b = (const float*)d_in[10];
    const float* w1    = (const float*)d_in[11];
    const float* b1    = (const float*)d_in[12];
    const float* w2    = (const float*)d_in[13];
    const float* b2    = (const float*)d_in[14];

    float* x = (float*)d_ws;                                   // [SEQ,DIM] f32
    __hip_bfloat16* h   = (__hip_bfloat16*)(x + SEQ * DIM);    // [SEQ,DIM] bf16 (also o)
    __hip_bfloat16* qkv = h + SEQ * DIM;                       // [SEQ,QKVD]
    __hip_bfloat16* ffa = qkv + (size_t)SEQ * QKVD;            // [SEQ,FFN]
    __hip_bfloat16* qkv_wT = ffa + (size_t)SEQ * FFN;          // [L,QKVD,DIM]
    __hip_bfloat16* out_wT = qkv_wT + (size_t)2 * QKVD * DIM;  // [L,DIM,DIM]
    __hip_bfloat16* w1T    = out_wT + (size_t)2 * DIM * DIM;   // [L,FFN,DIM]
    __hip_bfloat16* w2T    = w1T + (size_t)2 * FFN * DIM;      // [L,DIM,FFN]

    transpose_w<<<dim3(QKVD / 32, DIM / 32, 2), 256, 0, stream>>>(qkv_w, qkv_wT, DIM, QKVD);
    transpose_w<<<dim3(DIM / 32, DIM / 32, 2), 256, 0, stream>>>(out_w, out_wT, DIM, DIM);
    transpose_w<<<dim3(FFN / 32, DIM / 32, 2), 256, 0, stream>>>(w1, w1T, DIM, FFN);
    transpose_w<<<dim3(DIM / 32, FFN / 32, 2), 256, 0, stream>>>(w2, w2T, FFN, DIM);

    embed_kernel<<<SEQ * DIM / 256, 256, 0, stream>>>(idx, emb, pe, x);

    for (int l = 0; l < 2; ++l) {
        ln_kernel<<<SEQ, 256, 0, stream>>>(x, ln1_s + l * DIM, ln1_b + l * DIM, h);
        mfma_gemm<128, false, false, true><<<dim3(QKVD / 128, SEQ / 128), 256, 0, stream>>>(
            (const ushort*)h, (const ushort*)(qkv_wT + (size_t)l * QKVD * DIM),
            qkv_b + l * QKVD, nullptr, qkv, SEQ, QKVD, DIM);
        flash_attn_kernel<<<dim3(32 * NH), 256, 0, stream>>>(
            (const ushort*)qkv, (ushort*)h);   // o aliases h
        mfma_gemm<64, false, true, false><<<dim3(DIM / 64, SEQ / 128), 256, 0, stream>>>(
            (const ushort*)h, (const ushort*)(out_wT + (size_t)l * DIM * DIM),
            out_b + l * DIM, x, x, SEQ, DIM, DIM);
        ln_kernel<<<SEQ, 256, 0, stream>>>(x, ln2_s + l * DIM, ln2_b + l * DIM, h);
        mfma_gemm<128, true, false, true><<<dim3(FFN / 128, SEQ / 128), 256, 0, stream>>>(
            (const ushort*)h, (const ushort*)(w1T + (size_t)l * FFN * DIM),
            b1 + l * FFN, nullptr, ffa, SEQ, FFN, DIM);
        float* cdst = (l == 1) ? (float*)d_out : x;
        mfma_gemm<64, false, true, false><<<dim3(DIM / 64, SEQ / 128), 256, 0, stream>>>(
            (const ushort*)ffa, (const ushort*)(w2T + (size_t)l * DIM * FFN),
            b2 + l * DIM, x, cdst, SEQ, DIM, FFN);
    }
}

// Round 4
// 565.974 us; speedup vs baseline: 1.1730x; 1.0907x over previous
//
#include <hip/hip_runtime.h>
#include <hip/hip_bf16.h>

// TransformerShardA: 2-layer GPT-2 shard. B=1, S=2048, D=768, H=12, hd=64,
// FFN=3072. Inputs f32 (+int idx), output f32 [1,2048,768].
//
// Round 10 (session R3->R4): GEMM restructure, attention frozen (R3 state).
//  - BK 32->64 (12 K-steps at K=768, was 24): halves barrier count.
//  - double-buffered LDS, ONE barrier per K-step: stage(t+1) issued via
//    global_load_lds BEFORE compute(t); the compiler's vmcnt(0) drain before
//    s_barrier then waits on loads that had a full 32-MFMA phase to land.
//  - T2 XOR swizzle (chunk j' = j ^ (row&7)) applied on BOTH sides: global
//    source pre-swizzled (gload_lds writes linearly, m173) + XOR on ds_read.
//    Kills the ~8-way ds_read_b128 conflicts of the old [row][32] layout,
//    which sit on the critical path at 1 wave/SIMD occupancy.
//  - 4 transpose launches merged into 1 (launch-gap trim).

#define SEQ 2048
#define DIM 768
#define NH 12
#define HD 64
#define FFN 3072
#define QKVD (3 * DIM)

typedef __attribute__((ext_vector_type(8))) short short8;
typedef __attribute__((ext_vector_type(4))) float f32x4;

__device__ __forceinline__ ushort bf16bits(float v) {
    __hip_bfloat16 hb = __float2bfloat16(v);
    return *reinterpret_cast<ushort*>(&hb);
}

// async 16B global->LDS (gfx950 global_load_lds_dwordx4)
__device__ __forceinline__ void gload_lds16(const ushort* g, ushort* l) {
    __builtin_amdgcn_global_load_lds(
        (const __attribute__((address_space(1))) void*)g,
        (__attribute__((address_space(3))) void*)l, 16, 0, 0);
}

// ---------------- embedding + positional ----------------
__global__ void embed_kernel(const int* __restrict__ idx,
                             const float* __restrict__ emb,
                             const float* __restrict__ pe,
                             float* __restrict__ x) {
    int i = blockIdx.x * 256 + threadIdx.x;
    int s = i / DIM;
    int d = i - s * DIM;
    x[i] = emb[idx[s] * DIM + d] + pe[i];
}

// ------------- merged weight transpose + cast: W[K,N] f32 -> WT[N,K] bf16 ---
// segments (flat blockIdx.x): qkv [0,3456) nx=72 K=768 N=2304
//                             out [3456,4608) nx=24 K=768 N=768
//                             w1  [4608,9216) nx=96 K=768 N=3072
//                             w2  [9216,13824) nx=24 K=3072 N=768
__global__ void transpose_all(
        const float* __restrict__ qkv_w, const float* __restrict__ out_w,
        const float* __restrict__ w1, const float* __restrict__ w2,
        __hip_bfloat16* __restrict__ qkv_wT, __hip_bfloat16* __restrict__ out_wT,
        __hip_bfloat16* __restrict__ w1T, __hip_bfloat16* __restrict__ w2T) {
    __shared__ float t[32][33];
    int b = blockIdx.x;
    const float* W; __hip_bfloat16* T; int K, N, nx;
    if (b < 3456)        { W = qkv_w; T = qkv_wT; K = 768;  N = 2304; nx = 72; }
    else if (b < 4608)   { b -= 3456; W = out_w; T = out_wT; K = 768; N = 768; nx = 24; }
    else if (b < 9216)   { b -= 4608; W = w1;    T = w1T;   K = 768;  N = 3072; nx = 96; }
    else                 { b -= 9216; W = w2;    T = w2T;   K = 3072; N = 768;  nx = 24; }
    int ny = K / 32;
    int bz = b / (nx * ny);
    int rem = b - bz * (nx * ny);
    int by = rem / nx, bx = rem - by * nx;

    const float* Wp = W + (size_t)bz * K * N;
    __hip_bfloat16* Tp = T + (size_t)bz * K * N;
    int k0 = by * 32, n0 = bx * 32;
    int r = threadIdx.x >> 3, c4 = (threadIdx.x & 7) * 4;
    float4 v = *(const float4*)&Wp[(size_t)(k0 + r) * N + n0 + c4];
    t[r][c4 + 0] = v.x; t[r][c4 + 1] = v.y; t[r][c4 + 2] = v.z; t[r][c4 + 3] = v.w;
    __syncthreads();
    __hip_bfloat16* dst = &Tp[(size_t)(n0 + r) * K + k0 + c4];
#pragma unroll
    for (int j = 0; j < 4; ++j) dst[j] = __float2bfloat16(t[c4 + j][r]);
}

// ---------------- LayerNorm (one block per row), writes bf16 ----------------
__global__ void ln_kernel(const float* __restrict__ x,
                          const float* __restrict__ sc,
                          const float* __restrict__ bi,
                          __hip_bfloat16* __restrict__ h) {
    int row = blockIdx.x, tid = threadIdx.x;
    __shared__ float red[256];
    const float* xr = x + row * DIM;
    float v[3];
#pragma unroll
    for (int i = 0; i < 3; ++i) v[i] = xr[tid + i * 256];
    float s = v[0] + v[1] + v[2];
    red[tid] = s; __syncthreads();
    for (int t = 128; t > 0; t >>= 1) {
        if (tid < t) red[tid] += red[tid + t];
        __syncthreads();
    }
    float mean = red[0] * (1.0f / DIM);
    __syncthreads();
    float q = 0.f;
#pragma unroll
    for (int i = 0; i < 3; ++i) { float d = v[i] - mean; q += d * d; }
    red[tid] = q; __syncthreads();
    for (int t = 128; t > 0; t >>= 1) {
        if (tid < t) red[tid] += red[tid + t];
        __syncthreads();
    }
    float rstd = rsqrtf(red[0] * (1.0f / DIM) + 1e-5f);
#pragma unroll
    for (int i = 0; i < 3; ++i) {
        int d = tid + i * 256;
        h[row * DIM + d] = __float2bfloat16((v[i] - mean) * rstd * sc[d] + bi[d]);
    }
}

// ---------------- bf16 MFMA GEMM: C = [res +] act(A@W + bias) ---------------
// 128xBN tile, 4 waves (2x2), BK=64, double-buffered LDS, 1 barrier/K-step.
// LDS layout: [row][8 chunks of 16B], chunk XOR-swizzled j' = j ^ (row&7).
// Staging: gload_lds writes chunk c linearly; global source pre-swizzled
// (col chunk = (c&7) ^ ((c>>3)&7)), so LDS holds the swizzled layout.
// Frag reads XOR with (lm&7) -> 8 distinct bank spans, 2 lanes/bank (free).
template <int BN, bool GELU, bool RES, bool OUTBF16>
__global__ __launch_bounds__(256) void mfma_gemm(
        const ushort* __restrict__ A, const ushort* __restrict__ WT,
        const float* __restrict__ bias, const float* __restrict__ res,
        void* __restrict__ Cout, int M, int N, int K) {
    constexpr int NT = BN / 32;          // B-frags per wave: 4 or 2
    constexpr int NBC = BN * 8 / 256;    // B chunks per thread: 4 or 2
    __shared__ ushort As[2][128 * 64];
    __shared__ ushort Bs[2][BN * 64];
    int tid = threadIdx.x;
    int w = tid >> 6, lane = tid & 63;
    int wm = (w >> 1) * 64, wn = (w & 1) * (BN / 2);
    int bm = blockIdx.y * 128, bn = blockIdx.x * BN;
    int lm = lane & 15, quad = lane >> 4;
    int jb = lm & 7;                     // frag-read swizzle key

    f32x4 acc[4][NT];
#pragma unroll
    for (int i = 0; i < 4; ++i)
#pragma unroll
        for (int j = 0; j < NT; ++j) acc[i][j] = {0.f, 0.f, 0.f, 0.f};

    // staging pointers: chunk c = i*256 + tid; row = c>>3; swz col chunk
    const ushort* gA[4];
    const ushort* gB[NBC];
#pragma unroll
    for (int i = 0; i < 4; ++i) {
        int c = i * 256 + tid;
        int row = c >> 3, j = (c & 7) ^ (row & 7);
        gA[i] = &A[(size_t)(bm + row) * K + j * 8];
    }
#pragma unroll
    for (int i = 0; i < NBC; ++i) {
        int c = i * 256 + tid;
        int row = c >> 3, j = (c & 7) ^ (row & 7);
        gB[i] = &WT[(size_t)(bn + row) * K + j * 8];
    }

    const int nk = K >> 6;

    // prologue: stage K-step 0 into buffer 0
#pragma unroll
    for (int i = 0; i < 4; ++i)
        gload_lds16(gA[i], &As[0][(i * 256 + tid) * 8]);
#pragma unroll
    for (int i = 0; i < NBC; ++i)
        gload_lds16(gB[i], &Bs[0][(i * 256 + tid) * 8]);
    __syncthreads();

    int p = 0;
    for (int t = 0; t < nk; ++t) {
        // stage next K-step into the other buffer (loads fly during compute)
        if (t + 1 < nk) {
            int k1 = (t + 1) << 6;
#pragma unroll
            for (int i = 0; i < 4; ++i)
                gload_lds16(gA[i] + k1, &As[p ^ 1][(i * 256 + tid) * 8]);
#pragma unroll
            for (int i = 0; i < NBC; ++i)
                gload_lds16(gB[i] + k1, &Bs[p ^ 1][(i * 256 + tid) * 8]);
        }

        // frag reads (XOR-swizzled) + 2x K=32 MFMA sub-steps
        short8 af[2][4], bw[2][NT];
#pragma unroll
        for (int kc = 0; kc < 2; ++kc) {
#pragma unroll
            for (int mt = 0; mt < 4; ++mt) {
                int row = wm + mt * 16 + lm;
                int j = (kc * 4 + quad) ^ jb;
                af[kc][mt] = *(const short8*)&As[p][row * 64 + j * 8];
            }
#pragma unroll
            for (int nt = 0; nt < NT; ++nt) {
                int row = wn + nt * 16 + lm;
                int j = (kc * 4 + quad) ^ jb;
                bw[kc][nt] = *(const short8*)&Bs[p][row * 64 + j * 8];
            }
        }
#pragma unroll
        for (int kc = 0; kc < 2; ++kc)
#pragma unroll
            for (int mt = 0; mt < 4; ++mt)
#pragma unroll
                for (int nt = 0; nt < NT; ++nt)
                    acc[mt][nt] = __builtin_amdgcn_mfma_f32_16x16x32_bf16(
                        af[kc][mt], bw[kc][nt], acc[mt][nt], 0, 0, 0);

        __syncthreads();   // drains vmcnt (stage t+1 had full compute to land)
        p ^= 1;
    }

    int q8 = quad * 8;
#pragma unroll
    for (int nt = 0; nt < NT; ++nt) {
        int col = bn + wn + nt * 16 + lm;
        float bv = bias[col];
#pragma unroll
        for (int mt = 0; mt < 4; ++mt) {
            int rowb = bm + wm + mt * 16 + (q8 >> 1);
#pragma unroll
            for (int r = 0; r < 4; ++r) {
                int row = rowb + r;
                float v = acc[mt][nt][r] + bv;
                if (GELU) v = 0.5f * v * (1.0f + erff(v * 0.70710678118654752f));
                if (RES) v += res[(size_t)row * N + col];
                if (OUTBF16)
                    ((__hip_bfloat16*)Cout)[(size_t)row * N + col] = __float2bfloat16(v);
                else
                    ((float*)Cout)[(size_t)row * N + col] = v;
            }
        }
    }
}

// ---------------- MFMA flash attention (unchanged from R3) ----------------
__global__ __launch_bounds__(256) void flash_attn_kernel(
        const ushort* __restrict__ qkv, ushort* __restrict__ o) {
    int bi = blockIdx.x;
    int qt = 31 - bi / NH, head = bi % NH;
    int tid = threadIdx.x, w = tid >> 6, lane = tid & 63;
    int ln16 = lane & 15, quad = lane >> 4;

    __shared__ ushort Ks[2][64 * 72];   // [key][dim], pad 8
    __shared__ ushort Vt[2][64 * 64];   // [dim][grp^swz][8], no pad
    __shared__ ushort Ps[4][16 * 72];   // per-wave [qrow][key], pad 8

    int skey[2], sc8;
    sc8 = (tid & 7) * 8;
    skey[0] = tid >> 3;
    skey[1] = (256 + tid) >> 3;

    short8 kst[2], vst[2];
    const ushort* kbase = qkv + DIM + head * HD + sc8;

    short8 qf[2];
    {
        const ushort* qp = &qkv[(size_t)(qt * 64 + w * 16 + ln16) * QKVD
                                + head * HD + quad * 8];
        qf[0] = *(const short8*)qp;
        qf[1] = *(const short8*)(qp + 32);
    }

#pragma unroll
    for (int hh = 0; hh < 2; ++hh) {
        const ushort* kp = kbase + (size_t)(0 * 64 + skey[hh]) * QKVD;
        kst[hh] = *(const short8*)kp;
        vst[hh] = *(const short8*)(kp + DIM);
    }
#pragma unroll
    for (int hh = 0; hh < 2; ++hh) {
        int key = skey[hh];
        *(short8*)&Ks[0][key * 72 + sc8] = kst[hh];
        int g0 = key >> 3, ke = key & 7;
#pragma unroll
        for (int j = 0; j < 8; ++j) {
            int r = sc8 + j;
            Vt[0][r * 64 + ((g0 ^ (r >> 3)) & 7) * 8 + ke] = ((ushort*)&vst[hh])[j];
        }
    }
    __syncthreads();

    float m_i = -1e30f, l_i = 0.f;
    f32x4 oacc[4];
#pragma unroll
    for (int mt = 0; mt < 4; ++mt) oacc[mt] = {0.f, 0.f, 0.f, 0.f};

    int cur = 0;
    for (int kt = 0; kt <= qt; ++kt) {
        bool pre = (kt < qt);
        if (pre) {
#pragma unroll
            for (int hh = 0; hh < 2; ++hh) {
                const ushort* kp = kbase + (size_t)((kt + 1) * 64 + skey[hh]) * QKVD;
                kst[hh] = *(const short8*)kp;
                vst[hh] = *(const short8*)(kp + DIM);
            }
        }

        f32x4 s[4];
#pragma unroll
        for (int mt = 0; mt < 4; ++mt) {
            s[mt] = {0.f, 0.f, 0.f, 0.f};
#pragma unroll
            for (int kc = 0; kc < 2; ++kc) {
                short8 kf = *(const short8*)&Ks[cur][(mt * 16 + ln16) * 72
                                                     + kc * 32 + quad * 8];
                s[mt] = __builtin_amdgcn_mfma_f32_16x16x32_bf16(
                    kf, qf[kc], s[mt], 0, 0, 0);
            }
        }

        int qrow = qt * 64 + w * 16 + ln16;
        float sv[4][4];
        if (kt == qt) {
#pragma unroll
            for (int mt = 0; mt < 4; ++mt)
#pragma unroll
                for (int r = 0; r < 4; ++r) {
                    int key = kt * 64 + mt * 16 + quad * 4 + r;
                    sv[mt][r] = (key > qrow) ? -1e30f : s[mt][r] * 0.125f;
                }
        } else {
#pragma unroll
            for (int mt = 0; mt < 4; ++mt)
#pragma unroll
                for (int r = 0; r < 4; ++r) sv[mt][r] = s[mt][r] * 0.125f;
        }

        float tmax = -1e30f;
#pragma unroll
        for (int mt = 0; mt < 4; ++mt)
#pragma unroll
            for (int r = 0; r < 4; ++r) tmax = fmaxf(tmax, sv[mt][r]);
        tmax = fmaxf(tmax, __shfl_xor(tmax, 16));
        tmax = fmaxf(tmax, __shfl_xor(tmax, 32));
        float m_new = fmaxf(m_i, tmax);
        float alpha = __expf(m_i - m_new);
        m_i = m_new;

        float ls = 0.f;
#pragma unroll
        for (int mt = 0; mt < 4; ++mt) {
            union { ushort u[4]; unsigned long long ull; } pk;
#pragma unroll
            for (int r = 0; r < 4; ++r) {
                float p = __expf(sv[mt][r] - m_new);
                ls += p;
                pk.u[r] = bf16bits(p);
            }
            *(unsigned long long*)&Ps[w][ln16 * 72 + mt * 16 + quad * 4] = pk.ull;
        }
        ls += __shfl_xor(ls, 16);
        ls += __shfl_xor(ls, 32);
        l_i = l_i * alpha + ls;

#pragma unroll
        for (int mt = 0; mt < 4; ++mt) {
            oacc[mt][0] *= alpha; oacc[mt][1] *= alpha;
            oacc[mt][2] *= alpha; oacc[mt][3] *= alpha;
        }

#pragma unroll
        for (int kc = 0; kc < 2; ++kc) {
            short8 pf = *(const short8*)&Ps[w][ln16 * 72 + kc * 32 + quad * 8];
#pragma unroll
            for (int mt = 0; mt < 4; ++mt) {
                int row = mt * 16 + ln16;
                int g = kc * 4 + quad;
                short8 vf = *(const short8*)&Vt[cur][row * 64
                                                     + ((g ^ (row >> 3)) & 7) * 8];
                oacc[mt] = __builtin_amdgcn_mfma_f32_16x16x32_bf16(
                    vf, pf, oacc[mt], 0, 0, 0);
            }
        }

        if (pre) {
            int nb = cur ^ 1;
#pragma unroll
            for (int hh = 0; hh < 2; ++hh) {
                int key = skey[hh];
                *(short8*)&Ks[nb][key * 72 + sc8] = kst[hh];
                int g0 = key >> 3, ke = key & 7;
#pragma unroll
                for (int j = 0; j < 8; ++j) {
                    int r = sc8 + j;
                    Vt[nb][r * 64 + ((g0 ^ (r >> 3)) & 7) * 8 + ke] =
                        ((ushort*)&vst[hh])[j];
                }
            }
        }
        __syncthreads();
        cur ^= 1;
    }

    float inv = 1.0f / l_i;
    int orow = qt * 64 + w * 16 + ln16;
#pragma unroll
    for (int mt = 0; mt < 4; ++mt)
#pragma unroll
        for (int r = 0; r < 4; ++r) {
            int dimc = head * HD + mt * 16 + quad * 4 + r;
            o[(size_t)orow * DIM + dimc] = bf16bits(oacc[mt][r] * inv);
        }
}

extern "C" void kernel_launch(void* const* d_in, const int* in_sizes, int n_in,
                              void* d_out, int out_size, void* d_ws, size_t ws_size,
                              hipStream_t stream) {
    const int*   idx   = (const int*)  d_in[0];
    const float* emb   = (const float*)d_in[1];
    const float* pe    = (const float*)d_in[2];
    const float* qkv_w = (const float*)d_in[3];
    const float* qkv_b = (const float*)d_in[4];
    const float* out_w = (const float*)d_in[5];
    const float* out_b = (const float*)d_in[6];
    const float* ln1_s = (const float*)d_in[7];
    const float* ln1_b = (const float*)d_in[8];
    const float* ln2_s = (const float*)d_in[9];
    const float* ln2_b = (const float*)d_in[10];
    const float* w1    = (const float*)d_in[11];
    const float* b1    = (const float*)d_in[12];
    const float* w2    = (const float*)d_in[13];
    const float* b2    = (const float*)d_in[14];

    float* x = (float*)d_ws;                                   // [SEQ,DIM] f32
    __hip_bfloat16* h   = (__hip_bfloat16*)(x + SEQ * DIM);    // [SEQ,DIM] bf16 (also o)
    __hip_bfloat16* qkv = h + SEQ * DIM;                       // [SEQ,QKVD]
    __hip_bfloat16* ffa = qkv + (size_t)SEQ * QKVD;            // [SEQ,FFN]
    __hip_bfloat16* qkv_wT = ffa + (size_t)SEQ * FFN;          // [L,QKVD,DIM]
    __hip_bfloat16* out_wT = qkv_wT + (size_t)2 * QKVD * DIM;  // [L,DIM,DIM]
    __hip_bfloat16* w1T    = out_wT + (size_t)2 * DIM * DIM;   // [L,FFN,DIM]
    __hip_bfloat16* w2T    = w1T + (size_t)2 * FFN * DIM;      // [L,DIM,FFN]

    transpose_all<<<13824, 256, 0, stream>>>(qkv_w, out_w, w1, w2,
                                             qkv_wT, out_wT, w1T, w2T);

    embed_kernel<<<SEQ * DIM / 256, 256, 0, stream>>>(idx, emb, pe, x);

    for (int l = 0; l < 2; ++l) {
        ln_kernel<<<SEQ, 256, 0, stream>>>(x, ln1_s + l * DIM, ln1_b + l * DIM, h);
        mfma_gemm<128, false, false, true><<<dim3(QKVD / 128, SEQ / 128), 256, 0, stream>>>(
            (const ushort*)h, (const ushort*)(qkv_wT + (size_t)l * QKVD * DIM),
            qkv_b + l * QKVD, nullptr, qkv, SEQ, QKVD, DIM);
        flash_attn_kernel<<<dim3(32 * NH), 256, 0, stream>>>(
            (const ushort*)qkv, (ushort*)h);   // o aliases h
        mfma_gemm<64, false, true, false><<<dim3(DIM / 64, SEQ / 128), 256, 0, stream>>>(
            (const ushort*)h, (const ushort*)(out_wT + (size_t)l * DIM * DIM),
            out_b + l * DIM, x, x, SEQ, DIM, DIM);
        ln_kernel<<<SEQ, 256, 0, stream>>>(x, ln2_s + l * DIM, ln2_b + l * DIM, h);
        mfma_gemm<128, true, false, true><<<dim3(FFN / 128, SEQ / 128), 256, 0, stream>>>(
            (const ushort*)h, (const ushort*)(w1T + (size_t)l * FFN * DIM),
            b1 + l * FFN, nullptr, ffa, SEQ, FFN, DIM);
        float* cdst = (l == 1) ? (float*)d_out : x;
        mfma_gemm<64, false, true, false><<<dim3(DIM / 64, SEQ / 128), 256, 0, stream>>>(
            (const ushort*)ffa, (const ushort*)(w2T + (size_t)l * DIM * FFN),
            b2 + l * DIM, x, cdst, SEQ, DIM, FFN);
    }
}